// Round 1
// baseline (322.057 us; speedup 1.0000x reference)
//
#include <hip/hip_runtime.h>

// DownSample fused: gather(knn) -> LayerNorm(C=128) -> Linear(128->256, bf16 MFMA) -> maxpool(k=16)
// Outputs concatenated: out[m,256] f32 | n_p[m,3] f32 | n_o[4] as f32
//
// Inputs (setup_inputs order):
// 0:p[n,3] 1:x[n,128] 2:o[4] 3:n_p[m,3] 4:knn_idx[m,16] 5:n_o[4] 6:norm_w[128] 7:norm_b[128] 8:W[256,128]

#define C_IN   128
#define C_OUT  256
#define KNN    16
#define LN_EPS 1e-5f

typedef __attribute__((ext_vector_type(8))) short  short8;
typedef __attribute__((ext_vector_type(8))) __bf16 bf16x8;
typedef __attribute__((ext_vector_type(4))) float  f32x4;

__device__ __forceinline__ short f2bf_bits(float f) {
    unsigned u = __float_as_uint(f);
    u += 0x7fffu + ((u >> 16) & 1u);   // round-to-nearest-even
    return (short)(u >> 16);
}

__global__ __launch_bounds__(256) void fused_kernel(
    const float* __restrict__ x, const int* __restrict__ knn,
    const float* __restrict__ nw, const float* __restrict__ nb,
    const float* __restrict__ W, float* __restrict__ out, int mq)
{
    __shared__ __align__(16) short Ash[16 * 136];   // 16 rows x 128 bf16, pad to 136

    const int tid  = threadIdx.x;
    const int lane = tid & 63;
    const int wave = tid >> 6;          // 4 waves: wave w owns out cols [w*64, w*64+64)
    const int m16  = lane & 15;         // A-row / B-col / D-col index
    const int qd   = lane >> 4;         // quad within wave

    // ---- B fragments: W[n][k] as bf16, resident in registers for the whole block ----
    // b_frag layout for mfma_f32_16x16x32_bf16: lane holds B[k=qd*8+j][n=lane&15]
    short8 bfrag[4][4];                 // [n-tile][k-step]
    #pragma unroll
    for (int t = 0; t < 4; ++t) {
        const int n = wave * 64 + t * 16 + m16;
        #pragma unroll
        for (int s = 0; s < 4; ++s) {
            const int k0 = s * 32 + qd * 8;
            const float4* wp = (const float4*)(W + n * C_IN + k0);
            float4 w0 = wp[0], w1 = wp[1];
            short8 b;
            b[0] = f2bf_bits(w0.x); b[1] = f2bf_bits(w0.y);
            b[2] = f2bf_bits(w0.z); b[3] = f2bf_bits(w0.w);
            b[4] = f2bf_bits(w1.x); b[5] = f2bf_bits(w1.y);
            b[6] = f2bf_bits(w1.z); b[7] = f2bf_bits(w1.w);
            bfrag[t][s] = b;
        }
    }

    // staging role: thread handles neighbor row srow, channel chunk schunk (8 ch)
    const int srow   = tid >> 4;        // 0..15
    const int schunk = tid & 15;        // 0..15
    float wv[8], bv[8];                 // layernorm affine params for this chunk (block-invariant)
    {
        const float4* wp = (const float4*)(nw + schunk * 8);
        const float4* bp = (const float4*)(nb + schunk * 8);
        float4 a0 = wp[0], a1 = wp[1], c0 = bp[0], c1 = bp[1];
        wv[0]=a0.x; wv[1]=a0.y; wv[2]=a0.z; wv[3]=a0.w;
        wv[4]=a1.x; wv[5]=a1.y; wv[6]=a1.z; wv[7]=a1.w;
        bv[0]=c0.x; bv[1]=c0.y; bv[2]=c0.z; bv[3]=c0.w;
        bv[4]=c1.x; bv[5]=c1.y; bv[6]=c1.z; bv[7]=c1.w;
    }

    for (int q = blockIdx.x; q < mq; q += gridDim.x) {
        // ---- stage: gather neighbor row + LayerNorm -> bf16 A-tile in LDS ----
        const int idx = knn[q * KNN + srow];
        const float4* xr = (const float4*)(x + (long long)idx * C_IN + schunk * 8);
        float4 v0 = xr[0], v1 = xr[1];
        float vals[8] = {v0.x, v0.y, v0.z, v0.w, v1.x, v1.y, v1.z, v1.w};
        float s = 0.f, ss = 0.f;
        #pragma unroll
        for (int j = 0; j < 8; ++j) { s += vals[j]; ss += vals[j] * vals[j]; }
        // reduce across the 16 lanes sharing this row (contiguous lanes)
        #pragma unroll
        for (int off = 1; off < 16; off <<= 1) {
            s  += __shfl_xor(s, off);
            ss += __shfl_xor(ss, off);
        }
        const float mu   = s * (1.f / 128.f);
        const float var  = ss * (1.f / 128.f) - mu * mu;
        const float rstd = rsqrtf(var + LN_EPS);
        short8 hb;
        #pragma unroll
        for (int j = 0; j < 8; ++j) {
            float h = (vals[j] - mu) * rstd * wv[j] + bv[j];
            hb[j] = f2bf_bits(h);
        }
        __syncthreads();   // previous iteration's A-tile reads complete
        *(short8*)&Ash[srow * 136 + schunk * 8] = hb;
        __syncthreads();   // A-tile visible

        // ---- MFMA: [16 nbrs x 128] @ [128 x 64 cols per wave] ----
        short8 afrag[4];
        #pragma unroll
        for (int s2 = 0; s2 < 4; ++s2)
            afrag[s2] = *(const short8*)&Ash[m16 * 136 + s2 * 32 + qd * 8];

        f32x4 acc[4] = {{0,0,0,0},{0,0,0,0},{0,0,0,0},{0,0,0,0}};
        #pragma unroll
        for (int s2 = 0; s2 < 4; ++s2) {
            bf16x8 a = __builtin_bit_cast(bf16x8, afrag[s2]);
            #pragma unroll
            for (int t = 0; t < 4; ++t)
                acc[t] = __builtin_amdgcn_mfma_f32_16x16x32_bf16(
                    a, __builtin_bit_cast(bf16x8, bfrag[t][s2]), acc[t], 0, 0, 0);
        }

        // ---- maxpool over the 16 neighbor rows (C layout: col=lane&15, row=qd*4+reg) ----
        float r[4];
        #pragma unroll
        for (int t = 0; t < 4; ++t) {
            float v = fmaxf(fmaxf(acc[t][0], acc[t][1]), fmaxf(acc[t][2], acc[t][3]));
            v = fmaxf(v, __shfl_xor(v, 16));
            v = fmaxf(v, __shfl_xor(v, 32));
            r[t] = v;   // per-column max for n-tile t, col = m16 (same in all lanes of the 16-group)
        }
        // lane writes col (qd*16 + m16) of this wave's 64-col span -> coalesced 256B store
        float vout = (qd == 0) ? r[0] : (qd == 1) ? r[1] : (qd == 2) ? r[2] : r[3];
        out[q * C_OUT + wave * 64 + lane] = vout;
    }
}

__global__ void tail_kernel(const float* __restrict__ n_p, const int* __restrict__ n_o,
                            float* __restrict__ out_np, float* __restrict__ out_no, int cnt)
{
    int i = blockIdx.x * blockDim.x + threadIdx.x;
    if (i < cnt) out_np[i] = n_p[i];
    if (i < 4)   out_no[i] = (float)n_o[i];
}

extern "C" void kernel_launch(void* const* d_in, const int* in_sizes, int n_in,
                              void* d_out, int out_size, void* d_ws, size_t ws_size,
                              hipStream_t stream)
{
    const float* x   = (const float*)d_in[1];
    const float* n_p = (const float*)d_in[3];
    const int*   knn = (const int*)  d_in[4];
    const int*   n_o = (const int*)  d_in[5];
    const float* nw  = (const float*)d_in[6];
    const float* nb  = (const float*)d_in[7];
    const float* W   = (const float*)d_in[8];
    float* out = (float*)d_out;

    const int mq    = in_sizes[4] / KNN;   // 50000
    const int npcnt = in_sizes[3];         // 150000
    float* out_np = out + (size_t)mq * C_OUT;
    float* out_no = out_np + npcnt;

    hipLaunchKernelGGL(fused_kernel, dim3(1024), dim3(256), 0, stream,
                       x, knn, nw, nb, W, out, mq);
    hipLaunchKernelGGL(tail_kernel, dim3((npcnt + 255) / 256), dim3(256), 0, stream,
                       n_p, n_o, out_np, out_no, npcnt);
}